// Round 7
// baseline (21.815 us; speedup 1.0000x reference)
//
#include <hip/hip_runtime.h>
#include <hip/hip_fp16.h>
#include <math.h>

#define BLOCK 256
#define WVS   4          // waves per block; one image per wave

typedef _Float16 h2v __attribute__((ext_vector_type(2)));

__device__ __forceinline__ float dot2h(unsigned a, unsigned b, float c) {
#if __has_builtin(__builtin_amdgcn_fdot2)
    return __builtin_amdgcn_fdot2(__builtin_bit_cast(h2v, a),
                                  __builtin_bit_cast(h2v, b), c, false);
#else
    h2v xa = __builtin_bit_cast(h2v, a), yb = __builtin_bit_cast(h2v, b);
    return c + (float)xa[0] * (float)yb[0] + (float)xa[1] * (float)yb[1];
#endif
}

__device__ __forceinline__ unsigned packh(float a, float b) {
    __half2 h = __float22half2_rn(make_float2(a, b));
    return __builtin_bit_cast(unsigned, h);
}

__device__ __forceinline__ unsigned pkadd(unsigned a, unsigned b) {
    __half2 r = __hadd2(__builtin_bit_cast(__half2, a), __builtin_bit_cast(__half2, b));
    return __builtin_bit_cast(unsigned, r);
}

__device__ __forceinline__ float rfl(float v) {
    return __builtin_bit_cast(float,
        __builtin_amdgcn_readfirstlane(__builtin_bit_cast(int, v)));
}

// native sin/cos: input in revolutions; fract first (range-safe)
__device__ __forceinline__ void nsincos(float r, float& s, float& c) {
#if __has_builtin(__builtin_amdgcn_sinf) && __has_builtin(__builtin_amdgcn_cosf) && __has_builtin(__builtin_amdgcn_fractf)
    float rf = __builtin_amdgcn_fractf(r);
    s = __builtin_amdgcn_sinf(rf);
    c = __builtin_amdgcn_cosf(rf);
#else
    float rf = r - floorf(r);
    __sincosf(rf * 6.2831853071795864f, &s, &c);
#endif
}

// f32 add-reduce across 64 lanes via DPP, broadcast via readlane 63
template <int CTRL, int RMASK>
__device__ __forceinline__ float dppadd(float x) {
    int t = __builtin_amdgcn_update_dpp(0, __builtin_bit_cast(int, x),
                                        CTRL, RMASK, 0xf, false);
    return x + __builtin_bit_cast(float, t);
}
__device__ __forceinline__ float wave_sum64(float x) {
    x = dppadd<0x111, 0xf>(x);   // row_shr:1
    x = dppadd<0x112, 0xf>(x);   // row_shr:2
    x = dppadd<0x114, 0xf>(x);   // row_shr:4
    x = dppadd<0x118, 0xf>(x);   // row_shr:8
    x = dppadd<0x142, 0xa>(x);   // row_bcast:15
    x = dppadd<0x143, 0xc>(x);   // row_bcast:31
    return __builtin_bit_cast(float,
        __builtin_amdgcn_readlane(__builtin_bit_cast(int, x), 63));
}

// static-index select of L[j], j in [0,10)
__device__ __forceinline__ float sel10(const float L[10], int j) {
    float a0 = (j & 1) ? L[1] : L[0];
    float a2 = (j & 1) ? L[3] : L[2];
    float a4 = (j & 1) ? L[5] : L[4];
    float a6 = (j & 1) ? L[7] : L[6];
    float a8 = (j & 1) ? L[9] : L[8];
    float b0 = (j & 2) ? a2 : a0;
    float b4 = (j & 2) ? a6 : a4;
    float c0 = (j & 4) ? b4 : b0;
    return (j & 8) ? a8 : c0;
}

__global__ __launch_bounds__(BLOCK) void quanv_fused7(
    const float* __restrict__ x,
    const float* __restrict__ conv_w,
    const float* __restrict__ conv_b,
    const float* __restrict__ bn_gamma,
    const float* __restrict__ bn_beta,
    const float* __restrict__ bn_mean,
    const float* __restrict__ bn_var,
    const float* __restrict__ sw_p,
    const float* __restrict__ theta,
    const float* __restrict__ lin_w,
    const float* __restrict__ lin_b,
    const float* __restrict__ log_scale_p,
    float* __restrict__ out)
{
    // weights as k-pairs: [kk=k/2][p][k&1][c]  (uint4 read -> k=2kk,2kk+1 for patch p)
    __shared__ __half lw2[5 * 196 * 8];      // 15680 B
    __shared__ __half fsc[WVS][784];         //  6272 B (shortcut feats, c-major)

    const int t = threadIdx.x;
    const int lane = t & 63, wv = t >> 6;
    const int img = blockIdx.x * WVS + wv;
    const float INV2PI = 0.15915494309189535f;

    // ---- pixel loads first (8 x 8B per lane, one image) ----
    const float* xb = x + (size_t)img * 784;
    float2 px[4][2];
#pragma unroll
    for (int j = 0; j < 4; ++j) {
        int p = (j < 3) ? (lane + 64 * j) : (192 + (lane & 3));
        int i = p / 14, jj = p - i * 14;
        const int off = i * 56 + jj * 2;
        px[j][0] = *(const float2*)(xb + off);
        px[j][1] = *(const float2*)(xb + off + 28);
    }

    // ---- stage lin_w -> LDS fp16, k-paired layout ----
    for (int q = t; q < 1960; q += BLOCK) {
        float4 v = *(const float4*)(lin_w + q * 4);
        int k = q / 196;
        int p = q - k * 196;
        uint2 pk;
        pk.x = packh(v.x, v.y);
        pk.y = packh(v.z, v.w);
        *(uint2*)&lw2[(k >> 1) * 1568 + p * 8 + (k & 1) * 4] = pk;
    }

    // ---- uniform constants -> SGPRs via readfirstlane ----
    const float sw = sw_p[0];
    const float ls = rfl(log_scale_p[0]);
    float wfS[16], bfS[4];
#pragma unroll
    for (int c = 0; c < 4; ++c) {
        float scale = bn_gamma[c] * rsqrtf(bn_var[c] + 1e-5f);
        float sws = sw * scale;
#pragma unroll
        for (int k = 0; k < 4; ++k) wfS[c * 4 + k] = rfl(sws * conv_w[c * 4 + k]);
        bfS[c] = rfl(sw * (scale * (conv_b[c] - bn_mean[c]) + bn_beta[c]));
    }
    float thc[4];
#pragma unroll
    for (int w = 0; w < 4; ++w) thc[w] = rfl(theta[w] * INV2PI);
    float sE0, cE0, sF0, cF0, sE1, cE1, sF1, cF1;
    {
        float s, c;
        nsincos(theta[4] * INV2PI, s, c); sE0 = rfl(s); cE0 = rfl(c);
        nsincos(theta[5] * INV2PI, s, c); sF0 = rfl(s); cF0 = rfl(c);
        nsincos(theta[6] * INV2PI, s, c); sE1 = rfl(s); cE1 = rfl(c);
        nsincos(theta[7] * INV2PI, s, c); sF1 = rfl(s); cF1 = rfl(c);
    }

    // ---- pass 1: quantum feats -> regs, shortcut feats -> wave-private LDS ----
    unsigned qr[4][2];
#pragma unroll
    for (int j = 0; j < 4; ++j) {
        if (j == 3 && lane >= 4) break;
        const int p = (j < 3) ? (lane + 64 * j) : (192 + lane);
        const float x00 = px[j][0].x, x01 = px[j][0].y;
        const float x10 = px[j][1].x, x11 = px[j][1].y;
        float sa, ca, sb, cb;
        nsincos(fmaf(x00, INV2PI, thc[0]), sa, ca);
        nsincos(fmaf(x01, INV2PI, thc[1]), sb, cb);
        const float m0 = cE0 * ca - sE0 * (sa * sb);
        const float m1 = cF0 * (ca * cb) - sF0 * sb;
        nsincos(fmaf(x10, INV2PI, thc[2]), sa, ca);
        nsincos(fmaf(x11, INV2PI, thc[3]), sb, cb);
        const float m2 = cE1 * ca - sE1 * (sa * sb);
        const float m3 = cF1 * (ca * cb) - sF1 * sb;
        qr[j][0] = packh(m0, m1);
        qr[j][1] = packh(m2, m3);
#pragma unroll
        for (int c = 0; c < 4; ++c) {
            float v = fmaf(wfS[c * 4 + 0], x00,
                      fmaf(wfS[c * 4 + 1], x01,
                      fmaf(wfS[c * 4 + 2], x10,
                      fmaf(wfS[c * 4 + 3], x11, bfS[c]))));
            fsc[wv][c * 196 + p] = __float2half(v);
        }
    }

    __syncthreads();   // lw2 staged (cross-wave) + fsc drained

    // ---- matmul: per owned patch, feats = fsc + q(regs); 5 x ds_read_b128 weights ----
    float acc[10];
#pragma unroll
    for (int k = 0; k < 10; ++k) acc[k] = 0.f;

#pragma unroll
    for (int j = 0; j < 4; ++j) {
        if (j == 3 && lane >= 4) break;
        const int p = (j < 3) ? (lane + 64 * j) : (192 + lane);
        uint2 f = *(const uint2*)&fsc[wv][4 * p];
        const unsigned fa0 = pkadd(f.x, qr[j][0]);
        const unsigned fa1 = pkadd(f.y, qr[j][1]);
        const __half* wbase = &lw2[p * 8];
#pragma unroll
        for (int kk = 0; kk < 5; ++kk) {
            uint4 w = *(const uint4*)&wbase[kk * 1568];
            acc[2 * kk]     = dot2h(fa0, w.x, acc[2 * kk]);
            acc[2 * kk]     = dot2h(fa1, w.y, acc[2 * kk]);
            acc[2 * kk + 1] = dot2h(fa0, w.z, acc[2 * kk + 1]);
            acc[2 * kk + 1] = dot2h(fa1, w.w, acc[2 * kk + 1]);
        }
    }

    // ---- DPP reduce -> uniform logits; uniform softmax; lanes 0-9 store ----
    float L[10];
#pragma unroll
    for (int k = 0; k < 10; ++k)
        L[k] = (wave_sum64(acc[k]) + lin_b[k]) * ls;

    float m = L[0];
#pragma unroll
    for (int k = 1; k < 10; ++k) m = fmaxf(m, L[k]);
    float e = 0.f;
#pragma unroll
    for (int k = 0; k < 10; ++k) e += __expf(L[k] - m);
    const float lse = m + __logf(e);

    if (lane < 10)
        out[(size_t)img * 10 + lane] = sel10(L, lane) - lse;
}

extern "C" void kernel_launch(void* const* d_in, const int* in_sizes, int n_in,
                              void* d_out, int out_size, void* d_ws, size_t ws_size,
                              hipStream_t stream) {
    const float* x         = (const float*)d_in[0];
    const float* conv_w    = (const float*)d_in[1];
    const float* conv_b    = (const float*)d_in[2];
    const float* bn_gamma  = (const float*)d_in[3];
    const float* bn_beta   = (const float*)d_in[4];
    const float* bn_mean   = (const float*)d_in[5];
    const float* bn_var    = (const float*)d_in[6];
    const float* sw        = (const float*)d_in[7];
    const float* theta     = (const float*)d_in[8];
    const float* lin_w     = (const float*)d_in[9];
    const float* lin_b     = (const float*)d_in[10];
    const float* log_scale = (const float*)d_in[11];
    float* out = (float*)d_out;

    const int B = in_sizes[0] / 784;                 // 8192
    dim3 grid(B / WVS), block(BLOCK);                // 2048 blocks
    hipLaunchKernelGGL(quanv_fused7, grid, block, 0, stream,
                       x, conv_w, conv_b, bn_gamma, bn_beta, bn_mean, bn_var,
                       sw, theta, lin_w, lin_b, log_scale, out);
}

// Round 8
// 21.168 us; speedup vs baseline: 1.0305x; 1.0305x over previous
//
#include <hip/hip_runtime.h>
#include <hip/hip_fp16.h>
#include <math.h>

#define BLOCK 512
#define WVS   8          // waves per block; each wave owns 2 images

typedef _Float16 h2v __attribute__((ext_vector_type(2)));

__device__ __forceinline__ float dot2h(unsigned a, unsigned b, float c) {
#if __has_builtin(__builtin_amdgcn_fdot2)
    return __builtin_amdgcn_fdot2(__builtin_bit_cast(h2v, a),
                                  __builtin_bit_cast(h2v, b), c, false);
#else
    h2v xa = __builtin_bit_cast(h2v, a), yb = __builtin_bit_cast(h2v, b);
    return c + (float)xa[0] * (float)yb[0] + (float)xa[1] * (float)yb[1];
#endif
}

__device__ __forceinline__ unsigned packh(float a, float b) {
    __half2 h = __float22half2_rn(make_float2(a, b));
    return __builtin_bit_cast(unsigned, h);
}

__device__ __forceinline__ unsigned pkadd(unsigned a, unsigned b) {
    __half2 r = __hadd2(__builtin_bit_cast(__half2, a), __builtin_bit_cast(__half2, b));
    return __builtin_bit_cast(unsigned, r);
}

__device__ __forceinline__ float rfl(float v) {
    return __builtin_bit_cast(float,
        __builtin_amdgcn_readfirstlane(__builtin_bit_cast(int, v)));
}

// native sin/cos: input in revolutions; fract first (range-safe)
__device__ __forceinline__ void nsincos(float r, float& s, float& c) {
#if __has_builtin(__builtin_amdgcn_sinf) && __has_builtin(__builtin_amdgcn_cosf) && __has_builtin(__builtin_amdgcn_fractf)
    float rf = __builtin_amdgcn_fractf(r);
    s = __builtin_amdgcn_sinf(rf);
    c = __builtin_amdgcn_cosf(rf);
#else
    float rf = r - floorf(r);
    __sincosf(rf * 6.2831853071795864f, &s, &c);
#endif
}

// f32 add-reduce across 64 lanes via DPP, broadcast via readlane 63
template <int CTRL, int RMASK>
__device__ __forceinline__ float dppadd(float x) {
    int t = __builtin_amdgcn_update_dpp(0, __builtin_bit_cast(int, x),
                                        CTRL, RMASK, 0xf, false);
    return x + __builtin_bit_cast(float, t);
}
__device__ __forceinline__ float wave_sum64(float x) {
    x = dppadd<0x111, 0xf>(x);   // row_shr:1
    x = dppadd<0x112, 0xf>(x);   // row_shr:2
    x = dppadd<0x114, 0xf>(x);   // row_shr:4
    x = dppadd<0x118, 0xf>(x);   // row_shr:8
    x = dppadd<0x142, 0xa>(x);   // row_bcast:15
    x = dppadd<0x143, 0xc>(x);   // row_bcast:31
    return __builtin_bit_cast(float,
        __builtin_amdgcn_readlane(__builtin_bit_cast(int, x), 63));
}

// static-index select of L[j], j in [0,10)
__device__ __forceinline__ float sel10(const float L[10], int j) {
    float a0 = (j & 1) ? L[1] : L[0];
    float a2 = (j & 1) ? L[3] : L[2];
    float a4 = (j & 1) ? L[5] : L[4];
    float a6 = (j & 1) ? L[7] : L[6];
    float a8 = (j & 1) ? L[9] : L[8];
    float b0 = (j & 2) ? a2 : a0;
    float b4 = (j & 2) ? a6 : a4;
    float c0 = (j & 4) ? b4 : b0;
    return (j & 8) ? a8 : c0;
}

__global__ __launch_bounds__(BLOCK) void quanv_fused8(
    const float* __restrict__ x,
    const float* __restrict__ conv_w,
    const float* __restrict__ conv_b,
    const float* __restrict__ bn_gamma,
    const float* __restrict__ bn_beta,
    const float* __restrict__ bn_mean,
    const float* __restrict__ bn_var,
    const float* __restrict__ sw_p,
    const float* __restrict__ theta,
    const float* __restrict__ lin_w,
    const float* __restrict__ lin_b,
    const float* __restrict__ log_scale_p,
    float* __restrict__ out)
{
    // weights as k-pairs: [kk=k/2][p][k&1][c]  (uint4 read -> k=2kk,2kk+1)
    __shared__ __half lw2[5 * 196 * 8];      // 15680 B
    __shared__ __half fsc[WVS][2][784];      // 25088 B (shortcut feats, c-major)

    const int t = threadIdx.x;
    const int lane = t & 63, wv = t >> 6;
    const int img0 = (blockIdx.x * WVS + wv) * 2;
    const float INV2PI = 0.15915494309189535f;

    // ---- both images' pixel loads first ----
    const float* xb0 = x + (size_t)img0 * 784;
    const float* xb1 = xb0 + 784;
    float2 pxa[4][2], pxb[4][2];
#pragma unroll
    for (int j = 0; j < 4; ++j) {
        int p = (j < 3) ? (lane + 64 * j) : (192 + (lane & 3));
        int i = p / 14, jj = p - i * 14;
        const int off = i * 56 + jj * 2;
        pxa[j][0] = *(const float2*)(xb0 + off);
        pxa[j][1] = *(const float2*)(xb0 + off + 28);
        pxb[j][0] = *(const float2*)(xb1 + off);
        pxb[j][1] = *(const float2*)(xb1 + off + 28);
    }

    // ---- stage lin_w -> LDS fp16, k-paired layout ----
    for (int q = t; q < 1960; q += BLOCK) {
        float4 v = *(const float4*)(lin_w + q * 4);
        int k = q / 196;
        int p = q - k * 196;
        uint2 pk;
        pk.x = packh(v.x, v.y);
        pk.y = packh(v.z, v.w);
        *(uint2*)&lw2[(k >> 1) * 1568 + p * 8 + (k & 1) * 4] = pk;
    }

    // ---- uniform constants -> SGPRs via readfirstlane ----
    const float sw = sw_p[0];
    const float ls = rfl(log_scale_p[0]);
    float wfS[16], bfS[4];
#pragma unroll
    for (int c = 0; c < 4; ++c) {
        float scale = bn_gamma[c] * rsqrtf(bn_var[c] + 1e-5f);
        float sws = sw * scale;
#pragma unroll
        for (int k = 0; k < 4; ++k) wfS[c * 4 + k] = rfl(sws * conv_w[c * 4 + k]);
        bfS[c] = rfl(sw * (scale * (conv_b[c] - bn_mean[c]) + bn_beta[c]));
    }
    float thc[4];
#pragma unroll
    for (int w = 0; w < 4; ++w) thc[w] = rfl(theta[w] * INV2PI);
    float sE0, cE0, sF0, cF0, sE1, cE1, sF1, cF1;
    {
        float s, c;
        nsincos(theta[4] * INV2PI, s, c); sE0 = rfl(s); cE0 = rfl(c);
        nsincos(theta[5] * INV2PI, s, c); sF0 = rfl(s); cF0 = rfl(c);
        nsincos(theta[6] * INV2PI, s, c); sE1 = rfl(s); cE1 = rfl(c);
        nsincos(theta[7] * INV2PI, s, c); sF1 = rfl(s); cF1 = rfl(c);
    }

    // ---- pass 1 (both images): quantum feats -> regs, shortcut -> LDS ----
    unsigned qra[4][2], qrb[4][2];
#pragma unroll
    for (int j = 0; j < 4; ++j) {
        if (j == 3 && lane >= 4) break;
        const int p = (j < 3) ? (lane + 64 * j) : (192 + lane);
        {
            const float x00 = pxa[j][0].x, x01 = pxa[j][0].y;
            const float x10 = pxa[j][1].x, x11 = pxa[j][1].y;
            float sa, ca, sb, cb;
            nsincos(fmaf(x00, INV2PI, thc[0]), sa, ca);
            nsincos(fmaf(x01, INV2PI, thc[1]), sb, cb);
            const float m0 = cE0 * ca - sE0 * (sa * sb);
            const float m1 = cF0 * (ca * cb) - sF0 * sb;
            nsincos(fmaf(x10, INV2PI, thc[2]), sa, ca);
            nsincos(fmaf(x11, INV2PI, thc[3]), sb, cb);
            const float m2 = cE1 * ca - sE1 * (sa * sb);
            const float m3 = cF1 * (ca * cb) - sF1 * sb;
            qra[j][0] = packh(m0, m1);
            qra[j][1] = packh(m2, m3);
#pragma unroll
            for (int c = 0; c < 4; ++c) {
                float v = fmaf(wfS[c * 4 + 0], x00,
                          fmaf(wfS[c * 4 + 1], x01,
                          fmaf(wfS[c * 4 + 2], x10,
                          fmaf(wfS[c * 4 + 3], x11, bfS[c]))));
                fsc[wv][0][c * 196 + p] = __float2half(v);
            }
        }
        {
            const float x00 = pxb[j][0].x, x01 = pxb[j][0].y;
            const float x10 = pxb[j][1].x, x11 = pxb[j][1].y;
            float sa, ca, sb, cb;
            nsincos(fmaf(x00, INV2PI, thc[0]), sa, ca);
            nsincos(fmaf(x01, INV2PI, thc[1]), sb, cb);
            const float m0 = cE0 * ca - sE0 * (sa * sb);
            const float m1 = cF0 * (ca * cb) - sF0 * sb;
            nsincos(fmaf(x10, INV2PI, thc[2]), sa, ca);
            nsincos(fmaf(x11, INV2PI, thc[3]), sb, cb);
            const float m2 = cE1 * ca - sE1 * (sa * sb);
            const float m3 = cF1 * (ca * cb) - sF1 * sb;
            qrb[j][0] = packh(m0, m1);
            qrb[j][1] = packh(m2, m3);
#pragma unroll
            for (int c = 0; c < 4; ++c) {
                float v = fmaf(wfS[c * 4 + 0], x00,
                          fmaf(wfS[c * 4 + 1], x01,
                          fmaf(wfS[c * 4 + 2], x10,
                          fmaf(wfS[c * 4 + 3], x11, bfS[c]))));
                fsc[wv][1][c * 196 + p] = __float2half(v);
            }
        }
    }

    __syncthreads();   // lw2 staged (cross-wave) + own fsc drained

    // ---- joint matmul: weights read once, used for both images ----
    float acc0[10], acc1[10];
#pragma unroll
    for (int k = 0; k < 10; ++k) { acc0[k] = 0.f; acc1[k] = 0.f; }

#pragma unroll
    for (int j = 0; j < 4; ++j) {
        if (j == 3 && lane >= 4) break;
        const int p = (j < 3) ? (lane + 64 * j) : (192 + lane);
        uint2 f0 = *(const uint2*)&fsc[wv][0][4 * p];
        uint2 f1 = *(const uint2*)&fsc[wv][1][4 * p];
        const unsigned fa0 = pkadd(f0.x, qra[j][0]);
        const unsigned fa1 = pkadd(f0.y, qra[j][1]);
        const unsigned fb0 = pkadd(f1.x, qrb[j][0]);
        const unsigned fb1 = pkadd(f1.y, qrb[j][1]);
        const __half* wbase = &lw2[p * 8];
#pragma unroll
        for (int kk = 0; kk < 5; ++kk) {
            uint4 w = *(const uint4*)&wbase[kk * 1568];
            acc0[2 * kk]     = dot2h(fa0, w.x, acc0[2 * kk]);
            acc0[2 * kk]     = dot2h(fa1, w.y, acc0[2 * kk]);
            acc0[2 * kk + 1] = dot2h(fa0, w.z, acc0[2 * kk + 1]);
            acc0[2 * kk + 1] = dot2h(fa1, w.w, acc0[2 * kk + 1]);
            acc1[2 * kk]     = dot2h(fb0, w.x, acc1[2 * kk]);
            acc1[2 * kk]     = dot2h(fb1, w.y, acc1[2 * kk]);
            acc1[2 * kk + 1] = dot2h(fb0, w.z, acc1[2 * kk + 1]);
            acc1[2 * kk + 1] = dot2h(fb1, w.w, acc1[2 * kk + 1]);
        }
    }

    // ---- DPP reduce -> uniform logits; uniform softmax ----
    float L0[10], L1[10];
#pragma unroll
    for (int k = 0; k < 10; ++k) {
        L0[k] = (wave_sum64(acc0[k]) + lin_b[k]) * ls;
        L1[k] = (wave_sum64(acc1[k]) + lin_b[k]) * ls;
    }

    float mA = L0[0], mB = L1[0];
#pragma unroll
    for (int k = 1; k < 10; ++k) { mA = fmaxf(mA, L0[k]); mB = fmaxf(mB, L1[k]); }
    float eA = 0.f, eB = 0.f;
#pragma unroll
    for (int k = 0; k < 10; ++k) {
        eA += __expf(L0[k] - mA);
        eB += __expf(L1[k] - mB);
    }
    const float lseA = mA + __logf(eA);
    const float lseB = mB + __logf(eB);

    // ---- store: lanes 0-9 -> img0, lanes 16-25 -> img1 ----
    const int j = lane & 15;
    if (lane < 10)
        out[(size_t)img0 * 10 + j] = sel10(L0, j) - lseA;
    else if (lane >= 16 && lane < 26)
        out[(size_t)(img0 + 1) * 10 + j] = sel10(L1, j) - lseB;
}

extern "C" void kernel_launch(void* const* d_in, const int* in_sizes, int n_in,
                              void* d_out, int out_size, void* d_ws, size_t ws_size,
                              hipStream_t stream) {
    const float* x         = (const float*)d_in[0];
    const float* conv_w    = (const float*)d_in[1];
    const float* conv_b    = (const float*)d_in[2];
    const float* bn_gamma  = (const float*)d_in[3];
    const float* bn_beta   = (const float*)d_in[4];
    const float* bn_mean   = (const float*)d_in[5];
    const float* bn_var    = (const float*)d_in[6];
    const float* sw        = (const float*)d_in[7];
    const float* theta     = (const float*)d_in[8];
    const float* lin_w     = (const float*)d_in[9];
    const float* lin_b     = (const float*)d_in[10];
    const float* log_scale = (const float*)d_in[11];
    float* out = (float*)d_out;

    const int B = in_sizes[0] / 784;                 // 8192
    dim3 grid(B / (WVS * 2)), block(BLOCK);          // 512 blocks
    hipLaunchKernelGGL(quanv_fused8, grid, block, 0, stream,
                       x, conv_w, conv_b, bn_gamma, bn_beta, bn_mean, bn_var,
                       sw, theta, lin_w, lin_b, log_scale, out);
}